// Round 1
// baseline (125.317 us; speedup 1.0000x reference)
//
#include <hip/hip_runtime.h>
#include <stdint.h>
#include <math.h>

// Kuramoto dynamics, B=65536 x N=60, 10 steps.
// R4: transposed-GEMM restructure. Compute C^T[osc][batch] = Ke . sin^T with
// K=16 MFMA (16x16x16_bf16): B-operand k-layout (k = 4*quad + j) == C/D row
// layout (row = 4*quad + reg), so the MFMA output layout IS the next step's
// B-input layout. The per-step LDS transpose round-trip + barrier + unpack
// perms of R3 are eliminated entirely (they were the latency-bound serial
// chain: VALUBusy 54%, MfmaUtil 22%, 1.3M LDS bank-conflict cycles).
// Ke becomes the loop-invariant A operand, preloaded once (hi/lo bf16 split).
// Numerics preserved from R3 verbatim:
//   - 3-pass split MFMA: AH.BH + AL.BH + AH.BL  (same three products)
//   - update: 4 separately-rounded f32 ops (#pragma clang fp contract(off))
//   - wrap: branch-free, boundary-exact (|x| >= f32(pi) predicate)
//   - HW __sincosf only on paths attenuated by eff_dt*scale ~1e-3

#define B_TOTAL 65536
#define NOSC 60
#define STEPS 10

using short4v = __attribute__((ext_vector_type(4))) short;
using floatx4 = __attribute__((ext_vector_type(4))) float;

#if __has_builtin(__builtin_amdgcn_perm)
__device__ __forceinline__ unsigned int perm_b32(unsigned int s0, unsigned int s1, unsigned int sel) {
    return __builtin_amdgcn_perm(s0, s1, sel);
}
#else
__device__ __forceinline__ unsigned int perm_b32(unsigned int s0, unsigned int s1, unsigned int sel) {
    unsigned long long pool = ((unsigned long long)s0 << 32) | s1;
    unsigned int r = 0;
#pragma unroll
    for (int b = 0; b < 4; ++b) {
        unsigned int s = (sel >> (8 * b)) & 0xff;
        r |= ((unsigned int)((pool >> (8 * s)) & 0xff)) << (8 * b);
    }
    return r;
}
#endif

__device__ __forceinline__ unsigned int fbits(float x)        { return __builtin_bit_cast(unsigned int, x); }
__device__ __forceinline__ float        bitsf(unsigned int u) { return __builtin_bit_cast(float, u); }

// 16x16x16 bf16 MFMA (K=16). Guarded: builtin if present, else inline asm
// (v_mfma_f32_16x16x16_bf16 exists on gfx950 per ISA ref §10).
#if __has_builtin(__builtin_amdgcn_mfma_f32_16x16x16bf16_1k)
__device__ __forceinline__ floatx4 mfma16(short4v a, short4v b, floatx4 c) {
    return __builtin_amdgcn_mfma_f32_16x16x16bf16_1k(a, b, c, 0, 0, 0);
}
#else
__device__ __forceinline__ floatx4 mfma16(short4v a, short4v b, floatx4 c) {
    asm("v_mfma_f32_16x16x16_bf16 %0, %1, %2, %0" : "+v"(c) : "v"(a), "v"(b));
    return c;
}
#endif

// pack bf16-hi(a) into low half, bf16-hi(b) into high half of one b32
__device__ __forceinline__ unsigned int pack_hi_pair(float a, float b) {
    return perm_b32(fbits(b), fbits(a), 0x07060302u);
}

__global__ __launch_bounds__(64, 2)
void kuramoto_kernel(const float* __restrict__ theta_in,
                     const float* __restrict__ Kmat,
                     const float* __restrict__ omega,
                     const float* __restrict__ p_kglobal,
                     const float* __restrict__ p_cmod,
                     const float* __restrict__ p_gate,
                     const float* __restrict__ p_slow,
                     const float* __restrict__ p_dsneg,
                     const float* __restrict__ p_relax,
                     float* __restrict__ theta_out,
                     float* __restrict__ coh_out)
{
    const int lane = threadIdx.x & 63;
    const int lidx = lane & 15;   // batch within tile / A-row lane
    const int quad = lane >> 4;   // 0..3

    const float kglobal = p_kglobal[0];
    const float cmod    = p_cmod[0];
    const float gate    = p_gate[0];
    const float slow    = p_slow[0];
    const float dsneg   = p_dsneg[0];
    const float relax   = p_relax[0];

    float eff_dt, scale;
    {
#pragma clang fp contract(off)
        const float a     = slow * relax;
        const float b     = 1.0f + a;
        const float crit  = 1.0f / b;
        eff_dt            = 0.1f * crit;
        const float boost = 1.0f + gate * dsneg;
        scale             = (kglobal * boost) / 60.0f;
    }

    const int batch0 = blockIdx.x * 16;
    const int brow   = (batch0 + lidx) * NOSC;

    // ---- A operand (loop-invariant): Ke = K*cmod in MFMA-A layout, hi/lo split.
    // A[m=i][k=j]: lane holds row i = nt*16 + lidx, k = kt*16 + quad*4 + j.
    // Ke rows are row-major in Kmat -> direct float4 loads, no transpose.
    short4v AH[4][4], AL[4][4];
#pragma unroll
    for (int nt = 0; nt < 4; ++nt) {
        const int i = nt * 16 + lidx;
        const bool okn = (i < NOSC);          // zero A rows >= 60 -> acc rows 60..63 = 0
#pragma unroll
        for (int kt = 0; kt < 4; ++kt) {
            const int k0 = kt * 16 + quad * 4;
            float kv[4];
            if (okn && (k0 + 3) < NOSC) {
                const float4 a = *(const float4*)(Kmat + i * NOSC + k0);
                kv[0] = a.x; kv[1] = a.y; kv[2] = a.z; kv[3] = a.w;
            } else {
#pragma unroll
                for (int j = 0; j < 4; ++j)
                    kv[j] = (okn && (k0 + j) < NOSC) ? Kmat[i * NOSC + k0 + j] : 0.0f;
            }
            short4v h, l;
#pragma unroll
            for (int j = 0; j < 4; ++j) {
                const float v = kv[j] * cmod;
                const unsigned int hb = fbits(v) & 0xffff0000u;
                const float rlo = v - bitsf(hb);
                h[j] = (short)(hb >> 16);
                l[j] = (short)(fbits(rlo) >> 16);
            }
            AH[nt][kt] = h;
            AL[nt][kt] = l;
        }
    }

    // ---- state in C/D layout of the transposed GEMM:
    // element (osc o = nt*16 + quad*4 + r, batch = batch0 + lidx)
    float th[4][4], sn[4][4], cn[4][4], omg[4][4];
#pragma unroll
    for (int nt = 0; nt < 4; ++nt) {
        const int o0 = nt * 16 + quad * 4;    // o0 in {0,4,..,56} or 60 (pad)
        if (o0 + 3 < NOSC) {
            const float4 tv = *(const float4*)(theta_in + brow + o0);
            const float4 ov = *(const float4*)(omega + o0);
            th[nt][0] = tv.x; th[nt][1] = tv.y; th[nt][2] = tv.z; th[nt][3] = tv.w;
            omg[nt][0] = ov.x; omg[nt][1] = ov.y; omg[nt][2] = ov.z; omg[nt][3] = ov.w;
        } else {
#pragma unroll
            for (int r = 0; r < 4; ++r) { th[nt][r] = 0.0f; omg[nt][r] = 0.0f; }
        }
#pragma unroll
        for (int r = 0; r < 4; ++r)
            __sincosf(th[nt][r], &sn[nt][r], &cn[nt][r]);
    }

    // wrap constants (boundary-exact, see R3 notes)
    const float PI_F = 3.14159274101257324f;
    const float C_HI = 6.28318548202514648f;    // f32(2pi)
    const float C_LO = -1.7484556e-7f;          // 2pi - C_HI (f64-accurate)

    for (int t = 0; t < STEPS; ++t) {
        floatx4 accS[4], accC[4];
#pragma unroll
        for (int nt = 0; nt < 4; ++nt) { accS[nt] = (floatx4)0.0f; accC[nt] = (floatx4)0.0f; }

#pragma unroll
        for (int kt = 0; kt < 4; ++kt) {
            // B operand for k-tile kt: B[k = kt*16 + quad*4 + j][n = lidx]
            // == this thread's own state at (nt==kt, r==j). Zero data movement.
            union PU { unsigned int u[2]; short4v v; };
            PU bsh, bsl, bch, bcl;
            float sl[4], cl[4];
#pragma unroll
            for (int r = 0; r < 4; ++r) {
                const unsigned int us = fbits(sn[kt][r]);
                sl[r] = sn[kt][r] - bitsf(us & 0xffff0000u);
                const unsigned int uc = fbits(cn[kt][r]);
                cl[r] = cn[kt][r] - bitsf(uc & 0xffff0000u);
            }
            bsh.u[0] = pack_hi_pair(sn[kt][0], sn[kt][1]);
            bsh.u[1] = pack_hi_pair(sn[kt][2], sn[kt][3]);
            bsl.u[0] = pack_hi_pair(sl[0], sl[1]);
            bsl.u[1] = pack_hi_pair(sl[2], sl[3]);
            bch.u[0] = pack_hi_pair(cn[kt][0], cn[kt][1]);
            bch.u[1] = pack_hi_pair(cn[kt][2], cn[kt][3]);
            bcl.u[0] = pack_hi_pair(cl[0], cl[1]);
            bcl.u[1] = pack_hi_pair(cl[2], cl[3]);

#pragma unroll
            for (int nt = 0; nt < 4; ++nt) {
                accS[nt] = mfma16(AH[nt][kt], bsh.v, accS[nt]);
                accS[nt] = mfma16(AL[nt][kt], bsh.v, accS[nt]);
                accS[nt] = mfma16(AH[nt][kt], bsl.v, accS[nt]);
                accC[nt] = mfma16(AH[nt][kt], bch.v, accC[nt]);
                accC[nt] = mfma16(AL[nt][kt], bch.v, accC[nt]);
                accC[nt] = mfma16(AH[nt][kt], bcl.v, accC[nt]);
            }
        }

        // ---- update: ref-exact association + boundary-exact wrap
        // accS[nt][r] = (Ke.sin)[osc nt*16+quad*4+r][batch lidx] -- all local.
#pragma unroll
        for (int nt = 0; nt < 4; ++nt) {
#pragma unroll
            for (int r = 0; r < 4; ++r) {
                const float S = accS[nt][r];
                const float C = accC[nt][r];
                const float coup = cn[nt][r] * S - sn[nt][r] * C;  // approx path: fma ok
                float nth;
                {
#pragma clang fp contract(off)
                    const float t1 = scale * coup;       // np: scale*coupling_sum
                    const float t2 = omg[nt][r] + t1;    // np: omega + ...
                    const float t3 = eff_dt * t2;        // np: eff_dt * (...)
                    nth = th[nt][r] + t3;                // np: th + ...
                }
                float n = 0.0f;
                n = (nth >=  PI_F) ?  1.0f : n;
                n = (nth <= -PI_F) ? -1.0f : n;
                float y = fmaf(n, -C_HI, nth);
                y = fmaf(n, -C_LO, y);
                th[nt][r] = y;
                __sincosf(y, &sn[nt][r], &cn[nt][r]);
            }
        }
    }

    // ---- epilogue: store wrapped theta (float4 per nt, pad tile skipped)
#pragma unroll
    for (int nt = 0; nt < 4; ++nt) {
        const int o0 = nt * 16 + quad * 4;
        if (o0 + 3 < NOSC) {
            float4 tv;
            tv.x = th[nt][0]; tv.y = th[nt][1]; tv.z = th[nt][2]; tv.w = th[nt][3];
            *(float4*)(theta_out + brow + o0) = tv;
        }
    }

    // ---- coherence: batch = lidx; thread holds 16 of its 60 osc, other 48
    // live in the 3 sibling quads -> 2 shfl_xor hops (16, 32) reduce.
    float pc = 0.0f, ps = 0.0f;
#pragma unroll
    for (int nt = 0; nt < 4; ++nt) {
        if (nt * 16 + quad * 4 < NOSC) {   // skip pad osc 60..63 (cos(0)=1!)
#pragma unroll
            for (int r = 0; r < 4; ++r) { pc += cn[nt][r]; ps += sn[nt][r]; }
        }
    }
    pc += __shfl_xor(pc, 16);
    ps += __shfl_xor(ps, 16);
    pc += __shfl_xor(pc, 32);
    ps += __shfl_xor(ps, 32);
    if (quad == 0) {
        const float cm = pc / 60.0f;
        const float sm = ps / 60.0f;
        coh_out[batch0 + lidx] = sqrtf(cm * cm + sm * sm);
    }
}

extern "C" void kernel_launch(void* const* d_in, const int* in_sizes, int n_in,
                              void* d_out, int out_size, void* d_ws, size_t ws_size,
                              hipStream_t stream) {
    const float* theta = (const float*)d_in[0];
    const float* Kmat  = (const float*)d_in[1];
    const float* omg   = (const float*)d_in[2];
    const float* kg    = (const float*)d_in[3];
    const float* cmod  = (const float*)d_in[4];
    const float* gate  = (const float*)d_in[5];
    const float* slow  = (const float*)d_in[6];
    const float* dsn   = (const float*)d_in[7];
    const float* relax = (const float*)d_in[8];
    float* out = (float*)d_out;

    kuramoto_kernel<<<dim3(B_TOTAL / 16), dim3(64), 0, stream>>>(
        theta, Kmat, omg, kg, cmod, gate, slow, dsn, relax,
        out, out + (size_t)B_TOTAL * NOSC);
}